// Round 8
// baseline (136.939 us; speedup 1.0000x reference)
//
#include <hip/hip_runtime.h>
#include <hip/hip_bf16.h>
#include <math.h>

#define BB 8
#define LL 2048
#define DD 128
#define DQKN 64
#define DVN 256
#define MTOT (BB*LL)
#define SCALE 0.08838834764831845f  // 128^-0.5
#define LOG2E 1.4426950408889634f
#define QSCALE (SCALE*LOG2E)

#define CHUNK 32
#define NCH (LL/CHUNK)   // 64
#define CT 4             // KV tiles (of 64) per attn chunk-block
#define NCHK 144         // chunks per batch = sum_{g=0..7} 4*(g+1)

typedef __attribute__((ext_vector_type(4))) float f32x4;
typedef __attribute__((ext_vector_type(8))) short s16x8;

__device__ __forceinline__ float sigmoidf_(float x){ return 1.f/(1.f+__expf(-x)); }
__device__ __forceinline__ float siluf_(float x){ return x/(1.f+__expf(-x)); }
__device__ __forceinline__ __hip_bfloat16 f2bf(float f){ return __float2bfloat16(f); }
__device__ __forceinline__ ushort f2bfu(float f){ __hip_bfloat16 h = __float2bfloat16(f); return *(const ushort*)&h; }
__device__ __forceinline__ float bf2f(ushort u){ union{unsigned i; float f;} v; v.i = ((unsigned)u)<<16; return v.f; }

__device__ __forceinline__ void gl_lds16(const __hip_bfloat16* g, void* l) {
    __builtin_amdgcn_global_load_lds(
        (const __attribute__((address_space(1))) void*)g,
        (__attribute__((address_space(3))) void*)l, 16, 0, 0);
}

// ---------------- fused: pack all weights + bias table (1 launch)
__global__ void pack_all(const float* __restrict__ Wqk, const float* __restrict__ Wv,
                         const float* __restrict__ Wrst, const float* __restrict__ Wu,
                         const float* __restrict__ Wh, const float* __restrict__ Uh,
                         const float* __restrict__ rel_bias,
                         __hip_bfloat16* __restrict__ WqkP, __hip_bfloat16* __restrict__ WvP,
                         __hip_bfloat16* __restrict__ WrstP, __hip_bfloat16* __restrict__ WuP,
                         __hip_bfloat16* __restrict__ WhP, __hip_bfloat16* __restrict__ UhP,
                         float* __restrict__ btab) {
    int blk = blockIdx.x;
    int l = threadIdx.x;  // 64
    if (blk == 272) {
        for (int n = l; n < LL; n += 64) {
            int bucket;
            if (n < 16) bucket = n;
            else {
                float v = logf((float)n * (1.0f/16.0f)) * (1.0f/logf(8.0f)) * 16.0f;
                bucket = 16 + (int)v;
                if (bucket > 31) bucket = 31;
            }
            btab[n] = rel_bias[bucket] * 8.0f * LOG2E;
        }
        return;
    }
    const float* W; __hip_bfloat16* Wp; int K, N;
    if (blk < 16)       { W=Wqk;  Wp=WqkP;  K=128; N=64; }
    else if (blk < 80)  { W=Wv;   Wp=WvP;   K=128; N=256; blk-=16; }
    else if (blk < 144) { W=Wrst; Wp=WrstP; K=128; N=256; blk-=80; }
    else if (blk < 176) { W=Wu;   Wp=WuP;   K=128; N=128; blk-=144; }
    else if (blk < 208) { W=Wh;   Wp=WhP;   K=128; N=128; blk-=176; }
    else                { W=Uh;   Wp=UhP;   K=256; N=128; blk-=208; }
    int k32 = blk % (K/32), n16 = blk / (K/32);
    int col = n16*16 + (l & 15);
    int krow = k32*32 + (l >> 4)*8;
    ushort tmp[8];
    #pragma unroll
    for (int j = 0; j < 8; ++j) tmp[j] = f2bfu(W[(size_t)(krow + j)*N + col]);
    *reinterpret_cast<uint4*>(Wp + ((size_t)blk*64 + l)*8) = *reinterpret_cast<uint4*>(tmp);
}

// ---------------- EMA chunked scan
__global__ __launch_bounds__(256) void ema_scanA(const float* __restrict__ x,
                                                 const float* __restrict__ alphas,
                                                 const float* __restrict__ damps,
                                                 float* __restrict__ sl) {
    int tid = blockIdx.x * 256 + threadIdx.x;   // 65536
    int d = tid & 127;
    int c = (tid >> 7) & (NCH - 1);
    int b = tid >> 13;
    float u[16], r[16];
    #pragma unroll
    for (int h = 0; h < 16; ++h) {
        float a = sigmoidf_(alphas[h]);
        r[h] = (1.f - a) * sigmoidf_(damps[h]);
        u[h] = 0.f;
    }
    const float* xp = x + ((size_t)b * LL + c * CHUNK) * DD + d;
    #pragma unroll 4
    for (int i = 0; i < CHUNK; ++i) {
        float xv = xp[(size_t)i * DD];
        #pragma unroll
        for (int h = 0; h < 16; ++h) u[h] = fmaf(r[h], u[h], xv);
    }
    float* slp = sl + ((size_t)b * NCH + c) * 16 * DD + d;
    #pragma unroll
    for (int h = 0; h < 16; ++h) slp[(size_t)h * DD] = u[h];
}

__global__ __launch_bounds__(256) void ema_scanB(const float* __restrict__ alphas,
                                                 const float* __restrict__ damps,
                                                 const float* __restrict__ sl,
                                                 float* __restrict__ carry) {
    int tid = blockIdx.x * 256 + threadIdx.x;   // 16384
    int d = tid & 127;
    int h = (tid >> 7) & 15;
    int b = tid >> 11;
    float a = sigmoidf_(alphas[h]);
    float r = (1.f - a) * sigmoidf_(damps[h]);
    float rC = r;
    #pragma unroll
    for (int q = 0; q < 5; ++q) rC *= rC;       // r^32
    const float* slp = sl + ((size_t)b * NCH * 16 + h) * DD + d;
    float* cp = carry + ((size_t)b * NCH * 16 + h) * DD + d;
    float u = 0.f;
    for (int c = 0; c < NCH; ++c) {
        cp[(size_t)c * 16 * DD] = u;
        u = slp[(size_t)c * 16 * DD] + rC * u;
    }
}

__global__ __launch_bounds__(256) void ema_scanC(const float* __restrict__ x,
                                                 const float* __restrict__ expansion,
                                                 const float* __restrict__ reduction,
                                                 const float* __restrict__ alphas,
                                                 const float* __restrict__ damps,
                                                 const float* __restrict__ carry,
                                                 __hip_bfloat16* __restrict__ emab,
                                                 __hip_bfloat16* __restrict__ xb) {
    int tid = blockIdx.x * 256 + threadIdx.x;   // 65536
    int d = tid & 127;
    int c = (tid >> 7) & (NCH - 1);
    int b = tid >> 13;
    float u[16], r[16], we[16];
    #pragma unroll
    for (int h = 0; h < 16; ++h) {
        float a = sigmoidf_(alphas[h]);
        r[h] = (1.f - a) * sigmoidf_(damps[h]);
        we[h] = reduction[h * DD + d] * a * expansion[h * DD + d];
        u[h] = carry[((size_t)b * NCH + c) * 16 * DD + (size_t)h * DD + d];
    }
    const float* xp = x + ((size_t)b * LL + c * CHUNK) * DD + d;
    __hip_bfloat16* ep = emab + ((size_t)b * LL + c * CHUNK) * DD + d;
    __hip_bfloat16* xbp = xb + ((size_t)b * LL + c * CHUNK) * DD + d;
    #pragma unroll 4
    for (int i = 0; i < CHUNK; ++i) {
        float xv = xp[(size_t)i * DD];
        float acc = 0.f;
        #pragma unroll
        for (int h = 0; h < 16; ++h) {
            u[h] = fmaf(r[h], u[h], xv);
            acc = fmaf(we[h], u[h], acc);
        }
        ep[(size_t)i * DD] = f2bf(acc);
        xbp[(size_t)i * DD] = f2bf(xv);
    }
}

// ---------------- QK GEMM: qk = silu(ema@W_qk+b); q=(qk*g0+b0)*QSCALE, k=qk*g1+b1
__global__ __launch_bounds__(256) void gemm_qk(const __hip_bfloat16* __restrict__ A,
        const __hip_bfloat16* __restrict__ Wp, const float* __restrict__ bias,
        const float* __restrict__ gamma, const float* __restrict__ beta,
        __hip_bfloat16* __restrict__ qb, __hip_bfloat16* __restrict__ kb) {
    __shared__ char AsB[64*256];
    const int row0 = blockIdx.x * 64;
    const int t = threadIdx.x, w = t>>6, lane = t&63, l16 = lane&15, l4 = lane>>4;
    #pragma unroll
    for (int p = 0; p < 4; ++p) {
        int idx = p*256 + t;
        int row = idx / 16, u = idx % 16;
        uint4 d = *reinterpret_cast<const uint4*>(A + (size_t)(row0+row)*DD + u*8);
        *reinterpret_cast<uint4*>(AsB + row*256 + ((u*16) ^ ((row&7)<<4))) = d;
    }
    __syncthreads();
    f32x4 acc[4];
    #pragma unroll
    for (int n = 0; n < 4; ++n) acc[n] = (f32x4){0.f,0.f,0.f,0.f};
    const int arow = w*16 + l16;
    #pragma unroll
    for (int k32 = 0; k32 < 4; ++k32) {
        s16x8 af = *reinterpret_cast<const s16x8*>(AsB + arow*256 + ((k32*64 + l4*16) ^ ((arow&7)<<4)));
        #pragma unroll
        for (int n = 0; n < 4; ++n) {
            s16x8 bfr = *reinterpret_cast<const s16x8*>(Wp + ((size_t)(n*4 + k32)*64 + lane)*8);
            acc[n] = __builtin_amdgcn_mfma_f32_16x16x32_bf16(af, bfr, acc[n], 0, 0, 0);
        }
    }
    #pragma unroll
    for (int n = 0; n < 4; ++n) {
        int col = n*16 + l16;
        float bb = bias[col];
        float g0 = gamma[col], g1 = gamma[DQKN + col];
        float be0 = beta[col], be1 = beta[DQKN + col];
        #pragma unroll
        for (int r = 0; r < 4; ++r) {
            int row = w*16 + l4*4 + r;
            float s = siluf_(acc[n][r] + bb);
            qb[(size_t)(row0+row)*DQKN + col] = f2bf((s*g0 + be0) * QSCALE);
            kb[(size_t)(row0+row)*DQKN + col] = f2bf(s*g1 + be1);
        }
    }
}

// ---------------- fused V+RST GEMM (grid.y: 0 = V->vT, 1 = RST row-major), N=256
__global__ __launch_bounds__(256) void gemm_vrst(const __hip_bfloat16* __restrict__ xb,
        const __hip_bfloat16* __restrict__ emab,
        const __hip_bfloat16* __restrict__ WvP, const __hip_bfloat16* __restrict__ WrstP,
        const float* __restrict__ b_v, const float* __restrict__ b_rst,
        __hip_bfloat16* __restrict__ vT, __hip_bfloat16* __restrict__ rstb) {
    __shared__ char AsB[64*256];
    const int mode = blockIdx.y;
    const __hip_bfloat16* A = mode ? emab : xb;
    const __hip_bfloat16* Wp = mode ? WrstP : WvP;
    const float* bias = mode ? b_rst : b_v;
    const int row0 = blockIdx.x * 64;
    const int t = threadIdx.x, w = t>>6, lane = t&63, l16 = lane&15, l4 = lane>>4;
    #pragma unroll
    for (int p = 0; p < 4; ++p) {
        int idx = p*256 + t;
        int row = idx / 16, u = idx % 16;
        uint4 d = *reinterpret_cast<const uint4*>(A + (size_t)(row0+row)*DD + u*8);
        *reinterpret_cast<uint4*>(AsB + row*256 + ((u*16) ^ ((row&7)<<4))) = d;
    }
    __syncthreads();
    f32x4 acc[16];
    #pragma unroll
    for (int n = 0; n < 16; ++n) acc[n] = (f32x4){0.f,0.f,0.f,0.f};
    const int arow = w*16 + l16;
    #pragma unroll
    for (int k32 = 0; k32 < 4; ++k32) {
        s16x8 af = *reinterpret_cast<const s16x8*>(AsB + arow*256 + ((k32*64 + l4*16) ^ ((arow&7)<<4)));
        #pragma unroll
        for (int n = 0; n < 16; ++n) {
            s16x8 bfr = *reinterpret_cast<const s16x8*>(Wp + ((size_t)(n*4 + k32)*64 + lane)*8);
            acc[n] = __builtin_amdgcn_mfma_f32_16x16x32_bf16(af, bfr, acc[n], 0, 0, 0);
        }
    }
    if (mode == 0) {
        int bb_i = row0 >> 11;
        int lpos0 = (row0 & 2047) + w*16 + l4*4;
        #pragma unroll
        for (int n = 0; n < 16; ++n) {
            int col = n*16 + l16;
            float bb = bias[col];
            ushort pk[4];
            #pragma unroll
            for (int r = 0; r < 4; ++r) pk[r] = f2bfu(siluf_(acc[n][r] + bb));
            *reinterpret_cast<ushort4*>(vT + ((size_t)bb_i*DVN + col)*LL + lpos0) = *reinterpret_cast<ushort4*>(pk);
        }
    } else {
        #pragma unroll
        for (int n = 0; n < 16; ++n) {
            int col = n*16 + l16;
            float bb = bias[col];
            #pragma unroll
            for (int r = 0; r < 4; ++r) {
                int row = w*16 + l4*4 + r;
                rstb[(size_t)(row0+row)*DVN + col] = f2bf(siluf_(acc[n][r] + bb));
            }
        }
    }
}

// ---------------- MFMA flash attention, split-KV CT=4, double-buffered gload_lds staging
__global__ __launch_bounds__(256) void attn_kernel(
    const __hip_bfloat16* __restrict__ qg, const __hip_bfloat16* __restrict__ kg,
    const __hip_bfloat16* __restrict__ vTg, const float* __restrict__ btab,
    __hip_bfloat16* __restrict__ aob, __hip_bfloat16* __restrict__ part_o,
    float* __restrict__ part_ml) {
    __shared__ __hip_bfloat16 Ks[2][64 * 64];   // linear fill; swizzle folded into global src
    __shared__ __hip_bfloat16 Vs[2][256 * 64];
    __shared__ __hip_bfloat16 Ps[4][16][72];
    __shared__ float btl[320];                  // extended: includes -inf for masked dlt<0
    const int cid = NCHK - 1 - (int)blockIdx.x; // big groups first
    const int b = blockIdx.y;
    int g = 0;
    while (cid >= 2*(g+1)*(g+2)) ++g;           // group = ti>>2
    const int rel = cid - 2*g*(g+1);
    const int ti = 4*g + rel/(g+1);
    const int cch = rel % (g+1);
    const int i0 = ti * 64;
    const int jlo = cch * (CT*64);
    int jhi = jlo + CT*64; { int je = (ti+1)*64; if (jhi > je) jhi = je; }
    const int nt = (jhi - jlo) >> 6;
    const int t = threadIdx.x;
    const int w = t >> 6, lane = t & 63;
    const int l16 = lane & 15, l4 = lane >> 4;
    char* KsB = (char*)Ks;
    char* VsB = (char*)Vs;

    const int dminE = i0 - jhi + 1;             // may be negative (diagonal chunks)
    const int cnt = (i0 + 63 - jlo) - dminE + 1;  // <= 319
    for (int idx = t; idx < cnt; idx += 256) {
        int dlt = dminE + idx;
        btl[idx] = (dlt >= 0) ? btab[dlt] : -1e30f;
    }

    const int irow = i0 + w * 16 + l16;
    s16x8 qf[2];
    qf[0] = *reinterpret_cast<const s16x8*>(qg + ((size_t)b * LL + irow) * DQKN + l4 * 8);
    qf[1] = *reinterpret_cast<const s16x8*>(qg + ((size_t)b * LL + irow) * DQKN + 32 + l4 * 8);

    f32x4 o[16];
    #pragma unroll
    for (int n16 = 0; n16 < 16; ++n16) o[n16] = (f32x4){0.f, 0.f, 0.f, 0.f};
    float m[4] = {-1e30f, -1e30f, -1e30f, -1e30f};
    float l[4] = {0.f, 0.f, 0.f, 0.f};

    // stage K/V tile into buffer BUF (async; LDS dest wave-uniform, swizzle on global src)
    #define STAGE(BUF, J0) { \
        _Pragma("unroll") for (int i = 0; i < 2; ++i) { \
            int base = w * 128 + i * 64; \
            int idx = base + lane; \
            int row = idx >> 3; \
            int c16 = (idx & 7) ^ (row & 7); \
            gl_lds16(kg + ((size_t)b * LL + (J0) + row) * DQKN + c16 * 8, KsB + (BUF)*8192 + base * 16); } \
        _Pragma("unroll") for (int i = 0; i < 8; ++i) { \
            int base = w * 512 + i * 64; \
            int idx = base + lane; \
            int n = idx >> 3; \
            int c16 = (idx & 7) ^ (n & 7); \
            gl_lds16(vTg + ((size_t)b * DVN + n) * LL + (J0) + c16 * 8, VsB + (BUF)*32768 + base * 16); } }

    STAGE(0, jlo);
    __syncthreads();                            // drain prologue staging

    for (int tt = 0; tt < nt; ++tt) {
        const int j0 = jlo + tt * 64;
        const int cur = tt & 1;
        if (tt + 1 < nt) STAGE(cur ^ 1, j0 + 64);   // async; lands during compute
        // QK^T (q pre-scaled by SCALE*LOG2E)
        f32x4 s[4];
        #pragma unroll
        for (int t16 = 0; t16 < 4; ++t16) s[t16] = (f32x4){0.f, 0.f, 0.f, 0.f};
        #pragma unroll
        for (int c = 0; c < 2; ++c) {
            #pragma unroll
            for (int t16 = 0; t16 < 4; ++t16) {
                int j = t16 * 16 + l16;
                s16x8 kf = *reinterpret_cast<const s16x8*>(KsB + cur*8192 + j * 128 + ((c * 64 + l4 * 16) ^ ((j & 7) << 4)));
                s[t16] = __builtin_amdgcn_mfma_f32_16x16x32_bf16(qf[c], kf, s[t16], 0, 0, 0);
            }
        }
        // bias+mask via extended table; row stats
        const int Cb = (i0 + w * 16 + l4 * 4) - (j0 + l16) - dminE;
        float sv[4][4];
        float rmax[4] = {-1e30f, -1e30f, -1e30f, -1e30f};
        #pragma unroll
        for (int t16 = 0; t16 < 4; ++t16) {
            #pragma unroll
            for (int r = 0; r < 4; ++r) {
                float val = s[t16][r] + btl[Cb + r - t16 * 16];
                sv[t16][r] = val;
                rmax[r] = fmaxf(rmax[r], val);
            }
        }
        #pragma unroll
        for (int off = 1; off < 16; off <<= 1) {
            #pragma unroll
            for (int r = 0; r < 4; ++r) rmax[r] = fmaxf(rmax[r], __shfl_xor(rmax[r], off));
        }
        bool need = (rmax[0] > m[0]) || (rmax[1] > m[1]) || (rmax[2] > m[2]) || (rmax[3] > m[3]);
        if (__any(need)) {
            float alpha[4];
            #pragma unroll
            for (int r = 0; r < 4; ++r) {
                float mn = fmaxf(m[r], rmax[r]);
                alpha[r] = exp2f(m[r] - mn);
                m[r] = mn;
                l[r] *= alpha[r];
            }
            #pragma unroll
            for (int n16 = 0; n16 < 16; ++n16) {
                #pragma unroll
                for (int r = 0; r < 4; ++r) o[n16][r] *= alpha[r];
            }
        }
        float psum[4] = {0.f, 0.f, 0.f, 0.f};
        #pragma unroll
        for (int t16 = 0; t16 < 4; ++t16) {
            #pragma unroll
            for (int r = 0; r < 4; ++r) {
                float p = exp2f(sv[t16][r] - m[r]);
                psum[r] += p;
                Ps[w][l4 * 4 + r][t16 * 16 + l16] = f2bf(p);
            }
        }
        #pragma unroll
        for (int off = 1; off < 16; off <<= 1) {
            #pragma unroll
            for (int r = 0; r < 4; ++r) psum[r] += __shfl_xor(psum[r], off);
        }
        #pragma unroll
        for (int r = 0; r < 4; ++r) l[r] += psum[r];
        // PV (Ps wave-private)
        #pragma unroll
        for (int c = 0; c < 2; ++c) {
            s16x8 pf = *reinterpret_cast<const s16x8*>(&Ps[w][l16][c * 32 + l4 * 8]);
            #pragma unroll
            for (int n16 = 0; n16 < 16; ++n16) {
                int n = n16 * 16 + l16;
                s16x8 vf = *reinterpret_cast<const s16x8*>(VsB + cur*32768 + n * 128 + ((c * 64 + l4 * 16) ^ ((n & 7) << 4)));
                o[n16] = __builtin_amdgcn_mfma_f32_16x16x32_bf16(pf, vf, o[n16], 0, 0, 0);
            }
        }
        __syncthreads();   // next-tile staging landed; all waves done reading cur
    }
    #undef STAGE
    if (ti < 4) {
        float invl[4];
        #pragma unroll
        for (int r = 0; r < 4; ++r) invl[r] = 1.f / l[r];
        #pragma unroll
        for (int n16 = 0; n16 < 16; ++n16) {
            #pragma unroll
            for (int r = 0; r < 4; ++r) {
                aob[((size_t)b * LL + i0 + w * 16 + l4 * 4 + r) * DVN + n16 * 16 + l16] = f2bf(o[n16][r] * invl[r]);
            }
        }
    } else {
        const size_t slot = (size_t)b * NCHK + cid;
        __hip_bfloat16* po = part_o + slot * (64 * 256);
        #pragma unroll
        for (int n16 = 0; n16 < 16; ++n16) {
            #pragma unroll
            for (int r = 0; r < 4; ++r)
                po[(size_t)(w * 16 + l4 * 4 + r) * 256 + n16 * 16 + l16] = f2bf(o[n16][r]);
        }
        if (l16 == 0) {
            #pragma unroll
            for (int r = 0; r < 4; ++r) {
                int row = w * 16 + l4 * 4 + r;
                part_ml[slot * 128 + row * 2]     = m[r];
                part_ml[slot * 128 + row * 2 + 1] = l[r];
            }
        }
    }
}

// ---------------- combine partials (ti >= 4), nc = ti/4+1 in [2,8], col-half split
__global__ __launch_bounds__(256) void attn_combine(const __hip_bfloat16* __restrict__ part_o,
                                                    const float* __restrict__ part_ml,
                                                    __hip_bfloat16* __restrict__ aob) {
    const int ti = 4 + (int)blockIdx.x;   // 4..31
    const int ch = blockIdx.y;            // column half
    const int b = blockIdx.z;
    const int g = ti >> 2;
    const int nc = g + 1;
    const int cid0 = 2*g*(g+1) + (ti - 4*g)*(g+1);
    const size_t slot0 = (size_t)b * NCHK + cid0;
    __shared__ float sW[8][64];
    __shared__ float sinvL[64];
    const int t = threadIdx.x;
    if (t < 64) {
        float M = -1e30f;
        for (int c = 0; c < nc; ++c)
            M = fmaxf(M, part_ml[(slot0 + c) * 128 + t * 2]);
        float L = 0.f;
        for (int c = 0; c < nc; ++c) {
            float wv = exp2f(part_ml[(slot0 + c) * 128 + t * 2] - M);
            sW[c][t] = wv;
            L += wv * part_ml[(slot0 + c) * 128 + t * 2 + 1];
        }
        sinvL[t] = 1.f / L;
    }
    __syncthreads();
    const int i0 = ti * 64;
    #pragma unroll
    for (int it = 0; it < 4; ++it) {
        int idx = it * 256 + t;           // 8-bf16 units over 64 x 128
        int row = idx >> 4, c8 = idx & 15;
        int colu = ch * 16 + c8;          // unit of 8 cols within 256
        float acc[8] = {0.f,0.f,0.f,0.f,0.f,0.f,0.f,0.f};
        for (int c = 0; c < nc; ++c) {
            float wv = sW[c][row];
            uint4 d = *reinterpret_cast<const uint4*>(part_o + (slot0 + c) * (size_t)(64*256) + row * 256 + colu * 8);
            const ushort* pp = (const ushort*)&d;
            #pragma unroll
            for (int j = 0; j < 8; ++j) acc[j] = fmaf(wv, bf2f(pp[j]), acc[j]);
        }
        float il = sinvL[row];
        ushort pk[8];
        #pragma unroll
        for (int j = 0; j < 8; ++j) pk[j] = f2bfu(acc[j] * il);
        *reinterpret_cast<uint4*>(aob + ((size_t)b * LL + i0 + row) * DVN + colu * 8) = *reinterpret_cast<uint4*>(pk);
    }
}

// ---------------- fused final, split by column half (grid.y)
__global__ __launch_bounds__(256) void final_mfma(
        const __hip_bfloat16* __restrict__ emab, const __hip_bfloat16* __restrict__ aob,
        const __hip_bfloat16* __restrict__ rstb, const float* __restrict__ x,
        const __hip_bfloat16* __restrict__ WhP, const __hip_bfloat16* __restrict__ UhP,
        const __hip_bfloat16* __restrict__ WuP, const float* __restrict__ bh,
        const float* __restrict__ bu, float* __restrict__ out) {
    __shared__ char As1[64*256];   // ema tile, K=128
    __shared__ char As2[64*512];   // gated tile, K=256
    const int row0 = blockIdx.x * 64;
    const int ch = blockIdx.y;     // cols [ch*64, ch*64+64)
    const int t = threadIdx.x, w = t>>6, lane = t&63, l16 = lane&15, l4 = lane>>4;
    #pragma unroll
    for (int p = 0; p < 4; ++p) {
        int idx = p*256 + t;
        int row = idx / 16, u = idx % 16;
        uint4 d = *reinterpret_cast<const uint4*>(emab + (size_t)(row0+row)*DD + u*8);
        *reinterpret_cast<uint4*>(As1 + row*256 + ((u*16) ^ ((row&7)<<4))) = d;
    }
    #pragma unroll
    for (int p = 0; p < 8; ++p) {
        int idx = p*256 + t;
        int row = idx / 32, u = idx % 32;
        uint4 da = *reinterpret_cast<const uint4*>(aob + (size_t)(row0+row)*DVN + u*8);
        uint4 dr = *reinterpret_cast<const uint4*>(rstb + (size_t)(row0+row)*DVN + u*8);
        const ushort* pa = (const ushort*)&da;
        const ushort* pr = (const ushort*)&dr;
        ushort gg[8];
        #pragma unroll
        for (int j = 0; j < 8; ++j) gg[j] = f2bfu(bf2f(pa[j]) * bf2f(pr[j]));
        *reinterpret_cast<uint4*>(As2 + row*512 + ((u*16) ^ ((row&7)<<4))) = *reinterpret_cast<uint4*>(gg);
    }
    __syncthreads();
    f32x4 acc1[4], acc2[4];
    #pragma unroll
    for (int n = 0; n < 4; ++n) { acc1[n] = (f32x4){0.f,0.f,0.f,0.f}; acc2[n] = (f32x4){0.f,0.f,0.f,0.f}; }
    const int arow = w*16 + l16;
    #pragma unroll
    for (int k32 = 0; k32 < 4; ++k32) {
        s16x8 af = *reinterpret_cast<const s16x8*>(As1 + arow*256 + ((k32*64 + l4*16) ^ ((arow&7)<<4)));
        #pragma unroll
        for (int n = 0; n < 4; ++n) {
            s16x8 bw = *reinterpret_cast<const s16x8*>(WhP + ((size_t)((ch*4+n)*4 + k32)*64 + lane)*8);
            acc1[n] = __builtin_amdgcn_mfma_f32_16x16x32_bf16(af, bw, acc1[n], 0, 0, 0);
            s16x8 bu2 = *reinterpret_cast<const s16x8*>(WuP + ((size_t)((ch*4+n)*4 + k32)*64 + lane)*8);
            acc2[n] = __builtin_amdgcn_mfma_f32_16x16x32_bf16(af, bu2, acc2[n], 0, 0, 0);
        }
    }
    #pragma unroll
    for (int k32 = 0; k32 < 8; ++k32) {
        s16x8 gf = *reinterpret_cast<const s16x8*>(As2 + arow*512 + ((k32*64 + l4*16) ^ ((arow&7)<<4)));
        #pragma unroll
        for (int n = 0; n < 4; ++n) {
            s16x8 bw = *reinterpret_cast<const s16x8*>(UhP + ((size_t)((ch*4+n)*8 + k32)*64 + lane)*8);
            acc1[n] = __builtin_amdgcn_mfma_f32_16x16x32_bf16(gf, bw, acc1[n], 0, 0, 0);
        }
    }
    #pragma unroll
    for (int n = 0; n < 4; ++n) {
        int col = ch*64 + n*16 + l16;
        float bbh = bh[col], bbu = bu[col];
        #pragma unroll
        for (int r = 0; r < 4; ++r) {
            int row = w*16 + l4*4 + r;
            size_t gidx = (size_t)(row0+row)*DD + col;
            float hh = siluf_(acc1[n][r] + bbh);
            float u = sigmoidf_(acc2[n][r] + bbu);
            float xv = x[gidx];
            out[gidx] = u*hh + (1.f-u)*xv;
        }
    }
}

extern "C" void kernel_launch(void* const* d_in, const int* in_sizes, int n_in,
                              void* d_out, int out_size, void* d_ws, size_t ws_size,
                              hipStream_t stream) {
    const float* x        = (const float*)d_in[0];
    const float* expansion= (const float*)d_in[1];
    const float* reduction= (const float*)d_in[2];
    const float* alphas   = (const float*)d_in[3];
    const float* damps    = (const float*)d_in[4];
    const float* rel_bias = (const float*)d_in[5];
    const float* W_qk     = (const float*)d_in[6];
    const float* b_qk     = (const float*)d_in[7];
    const float* gamma    = (const float*)d_in[8];
    const float* beta     = (const float*)d_in[9];
    const float* W_v      = (const float*)d_in[10];
    const float* b_v      = (const float*)d_in[11];
    const float* W_reset  = (const float*)d_in[12];
    const float* b_reset  = (const float*)d_in[13];
    const float* W_update = (const float*)d_in[14];
    const float* b_update = (const float*)d_in[15];
    const float* Wh       = (const float*)d_in[16];
    const float* Uh       = (const float*)d_in[17];
    const float* bh       = (const float*)d_in[18];
    float* out = (float*)d_out;

    char* base = (char*)d_ws;
    __hip_bfloat16* emab = (__hip_bfloat16*)base;  base += (size_t)MTOT * DD * 2;
    __hip_bfloat16* xb   = (__hip_bfloat16*)base;  base += (size_t)MTOT * DD * 2;
    __hip_bfloat16* qb   = (__hip_bfloat16*)base;  base += (size_t)MTOT * DQKN * 2;
    __hip_bfloat16* kb   = (__hip_bfloat16*)base;  base += (size_t)MTOT * DQKN * 2;
    __hip_bfloat16* vT   = (__hip_bfloat16*)base;  base += (size_t)MTOT * DVN * 2;
    __hip_bfloat16* rstb = (__hip_bfloat16*)base;  base += (size_t)MTOT * DVN * 2;
    __hip_bfloat16* aob  = (__hip_bfloat16*)base;  base += (size_t)MTOT * DVN * 2;
    float* btab  = (float*)base;                   base += (size_t)LL * 4;
    float* sl    = (float*)base;                   base += (size_t)BB * NCH * 16 * DD * 4;
    float* carry = (float*)base;                   base += (size_t)BB * NCH * 16 * DD * 4;
    __hip_bfloat16* WqkP = (__hip_bfloat16*)base;  base += (size_t)DD * DQKN * 2;
    __hip_bfloat16* WvP  = (__hip_bfloat16*)base;  base += (size_t)DD * DVN * 2;
    __hip_bfloat16* WrstP= (__hip_bfloat16*)base;  base += (size_t)DD * DVN * 2;
    __hip_bfloat16* WuP  = (__hip_bfloat16*)base;  base += (size_t)DD * DD * 2;
    __hip_bfloat16* WhP  = (__hip_bfloat16*)base;  base += (size_t)DD * DD * 2;
    __hip_bfloat16* UhP  = (__hip_bfloat16*)base;  base += (size_t)DVN * DD * 2;
    __hip_bfloat16* part_o = (__hip_bfloat16*)base; base += (size_t)BB * NCHK * 64 * 256 * 2;
    float* part_ml = (float*)base;                 base += (size_t)BB * NCHK * 128 * 4;

    pack_all<<<273, 64, 0, stream>>>(W_qk, W_v, W_reset, W_update, Wh, Uh, rel_bias,
                                     WqkP, WvP, WrstP, WuP, WhP, UhP, btab);

    ema_scanA<<<BB * NCH * DD / 256, 256, 0, stream>>>(x, alphas, damps, sl);
    ema_scanB<<<BB * 16 * DD / 256, 256, 0, stream>>>(alphas, damps, sl, carry);
    ema_scanC<<<BB * NCH * DD / 256, 256, 0, stream>>>(x, expansion, reduction, alphas, damps, carry, emab, xb);

    gemm_qk<<<MTOT/64, 256, 0, stream>>>(emab, WqkP, b_qk, gamma, beta, qb, kb);
    gemm_vrst<<<dim3(MTOT/64, 2), 256, 0, stream>>>(xb, emab, WvP, WrstP, b_v, b_reset, vT, rstb);

    attn_kernel<<<dim3(NCHK, BB), 256, 0, stream>>>(qb, kb, vT, btab, aob, part_o, part_ml);
    attn_combine<<<dim3(28, 2, BB), 256, 0, stream>>>(part_o, part_ml, aob);

    final_mfma<<<dim3(MTOT/64, 2), 256, 0, stream>>>(emab, aob, rstb, x, WhP, UhP, WuP, bh, b_update, out);
}

// Round 9
// 128.714 us; speedup vs baseline: 1.0639x; 1.0639x over previous
//
#include <hip/hip_runtime.h>
#include <hip/hip_bf16.h>
#include <math.h>

#define BB 8
#define LL 2048
#define DD 128
#define DQKN 64
#define DVN 256
#define MTOT (BB*LL)
#define SCALE 0.08838834764831845f  // 128^-0.5
#define LOG2E 1.4426950408889634f
#define QSCALE (SCALE*LOG2E)

#define CHUNK 32
#define NCH (LL/CHUNK)   // 64
#define CT 4             // KV tiles (of 64) per attn chunk-block
#define NCHK 144         // chunks per batch = sum_{g=0..7} 4*(g+1)

typedef __attribute__((ext_vector_type(4))) float f32x4;
typedef __attribute__((ext_vector_type(8))) short s16x8;

__device__ __forceinline__ float sigmoidf_(float x){ return 1.f/(1.f+__expf(-x)); }
__device__ __forceinline__ float siluf_(float x){ return x/(1.f+__expf(-x)); }
__device__ __forceinline__ __hip_bfloat16 f2bf(float f){ return __float2bfloat16(f); }
__device__ __forceinline__ ushort f2bfu(float f){ __hip_bfloat16 h = __float2bfloat16(f); return *(const ushort*)&h; }
__device__ __forceinline__ float bf2f(ushort u){ union{unsigned i; float f;} v; v.i = ((unsigned)u)<<16; return v.f; }

__device__ __forceinline__ void gl_lds16(const __hip_bfloat16* g, void* l) {
    __builtin_amdgcn_global_load_lds(
        (const __attribute__((address_space(1))) void*)g,
        (__attribute__((address_space(3))) void*)l, 16, 0, 0);
}

// ---------------- fused: pack all weights + bias table (1 launch)
__global__ void pack_all(const float* __restrict__ Wqk, const float* __restrict__ Wv,
                         const float* __restrict__ Wrst, const float* __restrict__ Wu,
                         const float* __restrict__ Wh, const float* __restrict__ Uh,
                         const float* __restrict__ rel_bias,
                         __hip_bfloat16* __restrict__ WqkP, __hip_bfloat16* __restrict__ WvP,
                         __hip_bfloat16* __restrict__ WrstP, __hip_bfloat16* __restrict__ WuP,
                         __hip_bfloat16* __restrict__ WhP, __hip_bfloat16* __restrict__ UhP,
                         float* __restrict__ btab) {
    int blk = blockIdx.x;
    int l = threadIdx.x;  // 64
    if (blk == 272) {
        for (int n = l; n < LL; n += 64) {
            int bucket;
            if (n < 16) bucket = n;
            else {
                float v = logf((float)n * (1.0f/16.0f)) * (1.0f/logf(8.0f)) * 16.0f;
                bucket = 16 + (int)v;
                if (bucket > 31) bucket = 31;
            }
            btab[n] = rel_bias[bucket] * 8.0f * LOG2E;
        }
        return;
    }
    const float* W; __hip_bfloat16* Wp; int K, N;
    if (blk < 16)       { W=Wqk;  Wp=WqkP;  K=128; N=64; }
    else if (blk < 80)  { W=Wv;   Wp=WvP;   K=128; N=256; blk-=16; }
    else if (blk < 144) { W=Wrst; Wp=WrstP; K=128; N=256; blk-=80; }
    else if (blk < 176) { W=Wu;   Wp=WuP;   K=128; N=128; blk-=144; }
    else if (blk < 208) { W=Wh;   Wp=WhP;   K=128; N=128; blk-=176; }
    else                { W=Uh;   Wp=UhP;   K=256; N=128; blk-=208; }
    int k32 = blk % (K/32), n16 = blk / (K/32);
    int col = n16*16 + (l & 15);
    int krow = k32*32 + (l >> 4)*8;
    ushort tmp[8];
    #pragma unroll
    for (int j = 0; j < 8; ++j) tmp[j] = f2bfu(W[(size_t)(krow + j)*N + col]);
    *reinterpret_cast<uint4*>(Wp + ((size_t)blk*64 + l)*8) = *reinterpret_cast<uint4*>(tmp);
}

// ---------------- EMA chunked scan
__global__ __launch_bounds__(256) void ema_scanA(const float* __restrict__ x,
                                                 const float* __restrict__ alphas,
                                                 const float* __restrict__ damps,
                                                 float* __restrict__ sl) {
    int tid = blockIdx.x * 256 + threadIdx.x;   // 65536
    int d = tid & 127;
    int c = (tid >> 7) & (NCH - 1);
    int b = tid >> 13;
    float u[16], r[16];
    #pragma unroll
    for (int h = 0; h < 16; ++h) {
        float a = sigmoidf_(alphas[h]);
        r[h] = (1.f - a) * sigmoidf_(damps[h]);
        u[h] = 0.f;
    }
    const float* xp = x + ((size_t)b * LL + c * CHUNK) * DD + d;
    #pragma unroll 4
    for (int i = 0; i < CHUNK; ++i) {
        float xv = xp[(size_t)i * DD];
        #pragma unroll
        for (int h = 0; h < 16; ++h) u[h] = fmaf(r[h], u[h], xv);
    }
    float* slp = sl + ((size_t)b * NCH + c) * 16 * DD + d;
    #pragma unroll
    for (int h = 0; h < 16; ++h) slp[(size_t)h * DD] = u[h];
}

__global__ __launch_bounds__(256) void ema_scanB(const float* __restrict__ alphas,
                                                 const float* __restrict__ damps,
                                                 const float* __restrict__ sl,
                                                 float* __restrict__ carry) {
    int tid = blockIdx.x * 256 + threadIdx.x;   // 16384
    int d = tid & 127;
    int h = (tid >> 7) & 15;
    int b = tid >> 11;
    float a = sigmoidf_(alphas[h]);
    float r = (1.f - a) * sigmoidf_(damps[h]);
    float rC = r;
    #pragma unroll
    for (int q = 0; q < 5; ++q) rC *= rC;       // r^32
    const float* slp = sl + ((size_t)b * NCH * 16 + h) * DD + d;
    float* cp = carry + ((size_t)b * NCH * 16 + h) * DD + d;
    float u = 0.f;
    #pragma unroll 8
    for (int c = 0; c < NCH; ++c) {
        cp[(size_t)c * 16 * DD] = u;
        u = slp[(size_t)c * 16 * DD] + rC * u;
    }
}

__global__ __launch_bounds__(256) void ema_scanC(const float* __restrict__ x,
                                                 const float* __restrict__ expansion,
                                                 const float* __restrict__ reduction,
                                                 const float* __restrict__ alphas,
                                                 const float* __restrict__ damps,
                                                 const float* __restrict__ carry,
                                                 __hip_bfloat16* __restrict__ emab,
                                                 __hip_bfloat16* __restrict__ xb) {
    int tid = blockIdx.x * 256 + threadIdx.x;   // 65536
    int d = tid & 127;
    int c = (tid >> 7) & (NCH - 1);
    int b = tid >> 13;
    float u[16], r[16], we[16];
    #pragma unroll
    for (int h = 0; h < 16; ++h) {
        float a = sigmoidf_(alphas[h]);
        r[h] = (1.f - a) * sigmoidf_(damps[h]);
        we[h] = reduction[h * DD + d] * a * expansion[h * DD + d];
        u[h] = carry[((size_t)b * NCH + c) * 16 * DD + (size_t)h * DD + d];
    }
    const float* xp = x + ((size_t)b * LL + c * CHUNK) * DD + d;
    __hip_bfloat16* ep = emab + ((size_t)b * LL + c * CHUNK) * DD + d;
    __hip_bfloat16* xbp = xb + ((size_t)b * LL + c * CHUNK) * DD + d;
    #pragma unroll 4
    for (int i = 0; i < CHUNK; ++i) {
        float xv = xp[(size_t)i * DD];
        float acc = 0.f;
        #pragma unroll
        for (int h = 0; h < 16; ++h) {
            u[h] = fmaf(r[h], u[h], xv);
            acc = fmaf(we[h], u[h], acc);
        }
        ep[(size_t)i * DD] = f2bf(acc);
        xbp[(size_t)i * DD] = f2bf(xv);
    }
}

// ---------------- QK GEMM: qk = silu(ema@W_qk+b); q=(qk*g0+b0)*QSCALE, k=qk*g1+b1
__global__ __launch_bounds__(256) void gemm_qk(const __hip_bfloat16* __restrict__ A,
        const __hip_bfloat16* __restrict__ Wp, const float* __restrict__ bias,
        const float* __restrict__ gamma, const float* __restrict__ beta,
        __hip_bfloat16* __restrict__ qb, __hip_bfloat16* __restrict__ kb) {
    __shared__ char AsB[64*256];
    const int row0 = blockIdx.x * 64;
    const int t = threadIdx.x, w = t>>6, lane = t&63, l16 = lane&15, l4 = lane>>4;
    #pragma unroll
    for (int p = 0; p < 4; ++p) {
        int idx = p*256 + t;
        int row = idx / 16, u = idx % 16;
        uint4 d = *reinterpret_cast<const uint4*>(A + (size_t)(row0+row)*DD + u*8);
        *reinterpret_cast<uint4*>(AsB + row*256 + ((u*16) ^ ((row&7)<<4))) = d;
    }
    __syncthreads();
    f32x4 acc[4];
    #pragma unroll
    for (int n = 0; n < 4; ++n) acc[n] = (f32x4){0.f,0.f,0.f,0.f};
    const int arow = w*16 + l16;
    #pragma unroll
    for (int k32 = 0; k32 < 4; ++k32) {
        s16x8 af = *reinterpret_cast<const s16x8*>(AsB + arow*256 + ((k32*64 + l4*16) ^ ((arow&7)<<4)));
        #pragma unroll
        for (int n = 0; n < 4; ++n) {
            s16x8 bfr = *reinterpret_cast<const s16x8*>(Wp + ((size_t)(n*4 + k32)*64 + lane)*8);
            acc[n] = __builtin_amdgcn_mfma_f32_16x16x32_bf16(af, bfr, acc[n], 0, 0, 0);
        }
    }
    #pragma unroll
    for (int n = 0; n < 4; ++n) {
        int col = n*16 + l16;
        float bb = bias[col];
        float g0 = gamma[col], g1 = gamma[DQKN + col];
        float be0 = beta[col], be1 = beta[DQKN + col];
        #pragma unroll
        for (int r = 0; r < 4; ++r) {
            int row = w*16 + l4*4 + r;
            float s = siluf_(acc[n][r] + bb);
            qb[(size_t)(row0+row)*DQKN + col] = f2bf((s*g0 + be0) * QSCALE);
            kb[(size_t)(row0+row)*DQKN + col] = f2bf(s*g1 + be1);
        }
    }
}

// ---------------- fused V+RST GEMM (grid.y: 0 = V->vT, 1 = RST row-major), N=256
__global__ __launch_bounds__(256) void gemm_vrst(const __hip_bfloat16* __restrict__ xb,
        const __hip_bfloat16* __restrict__ emab,
        const __hip_bfloat16* __restrict__ WvP, const __hip_bfloat16* __restrict__ WrstP,
        const float* __restrict__ b_v, const float* __restrict__ b_rst,
        __hip_bfloat16* __restrict__ vT, __hip_bfloat16* __restrict__ rstb) {
    __shared__ char AsB[64*256];
    const int mode = blockIdx.y;
    const __hip_bfloat16* A = mode ? emab : xb;
    const __hip_bfloat16* Wp = mode ? WrstP : WvP;
    const float* bias = mode ? b_rst : b_v;
    const int row0 = blockIdx.x * 64;
    const int t = threadIdx.x, w = t>>6, lane = t&63, l16 = lane&15, l4 = lane>>4;
    #pragma unroll
    for (int p = 0; p < 4; ++p) {
        int idx = p*256 + t;
        int row = idx / 16, u = idx % 16;
        uint4 d = *reinterpret_cast<const uint4*>(A + (size_t)(row0+row)*DD + u*8);
        *reinterpret_cast<uint4*>(AsB + row*256 + ((u*16) ^ ((row&7)<<4))) = d;
    }
    __syncthreads();
    f32x4 acc[16];
    #pragma unroll
    for (int n = 0; n < 16; ++n) acc[n] = (f32x4){0.f,0.f,0.f,0.f};
    const int arow = w*16 + l16;
    #pragma unroll
    for (int k32 = 0; k32 < 4; ++k32) {
        s16x8 af = *reinterpret_cast<const s16x8*>(AsB + arow*256 + ((k32*64 + l4*16) ^ ((arow&7)<<4)));
        #pragma unroll
        for (int n = 0; n < 16; ++n) {
            s16x8 bfr = *reinterpret_cast<const s16x8*>(Wp + ((size_t)(n*4 + k32)*64 + lane)*8);
            acc[n] = __builtin_amdgcn_mfma_f32_16x16x32_bf16(af, bfr, acc[n], 0, 0, 0);
        }
    }
    if (mode == 0) {
        int bb_i = row0 >> 11;
        int lpos0 = (row0 & 2047) + w*16 + l4*4;
        #pragma unroll
        for (int n = 0; n < 16; ++n) {
            int col = n*16 + l16;
            float bb = bias[col];
            ushort pk[4];
            #pragma unroll
            for (int r = 0; r < 4; ++r) pk[r] = f2bfu(siluf_(acc[n][r] + bb));
            *reinterpret_cast<ushort4*>(vT + ((size_t)bb_i*DVN + col)*LL + lpos0) = *reinterpret_cast<ushort4*>(pk);
        }
    } else {
        #pragma unroll
        for (int n = 0; n < 16; ++n) {
            int col = n*16 + l16;
            float bb = bias[col];
            #pragma unroll
            for (int r = 0; r < 4; ++r) {
                int row = w*16 + l4*4 + r;
                rstb[(size_t)(row0+row)*DVN + col] = f2bf(siluf_(acc[n][r] + bb));
            }
        }
    }
}

// ---------------- MFMA flash attention, split-KV CT=4, single-buffer gload_lds,
// defer-max (THR=8), psum via ones-MFMA
__global__ __launch_bounds__(256) void attn_kernel(
    const __hip_bfloat16* __restrict__ qg, const __hip_bfloat16* __restrict__ kg,
    const __hip_bfloat16* __restrict__ vTg, const float* __restrict__ btab,
    __hip_bfloat16* __restrict__ aob, __hip_bfloat16* __restrict__ part_o,
    float* __restrict__ part_ml) {
    __shared__ __hip_bfloat16 Ks[64 * 64];      // linear fill; swizzle folded into global src
    __shared__ __hip_bfloat16 Vs[256 * 64];
    __shared__ __hip_bfloat16 Ps[4][16][72];
    __shared__ float btl[320];                  // extended: -inf for masked dlt<0
    const int cid = NCHK - 1 - (int)blockIdx.x; // big groups first
    const int b = blockIdx.y;
    int g = 0;
    while (cid >= 2*(g+1)*(g+2)) ++g;           // group = ti>>2
    const int rel = cid - 2*g*(g+1);
    const int ti = 4*g + rel/(g+1);
    const int cch = rel % (g+1);
    const int i0 = ti * 64;
    const int jlo = cch * (CT*64);
    int jhi = jlo + CT*64; { int je = (ti+1)*64; if (jhi > je) jhi = je; }
    const int nt = (jhi - jlo) >> 6;
    const int t = threadIdx.x;
    const int w = t >> 6, lane = t & 63;
    const int l16 = lane & 15, l4 = lane >> 4;
    char* KsB = (char*)Ks;
    char* VsB = (char*)Vs;

    const int dminE = i0 - jhi + 1;             // may be negative (diagonal chunks)
    const int cnt = (i0 + 63 - jlo) - dminE + 1;  // <= 319
    for (int idx = t; idx < cnt; idx += 256) {
        int dlt = dminE + idx;
        btl[idx] = (dlt >= 0) ? btab[dlt] : -1e30f;
    }

    const int irow = i0 + w * 16 + l16;
    s16x8 qf[2];
    qf[0] = *reinterpret_cast<const s16x8*>(qg + ((size_t)b * LL + irow) * DQKN + l4 * 8);
    qf[1] = *reinterpret_cast<const s16x8*>(qg + ((size_t)b * LL + irow) * DQKN + 32 + l4 * 8);

    s16x8 ones;
    #pragma unroll
    for (int j = 0; j < 8; ++j) ones[j] = (short)0x3F80;   // bf16 1.0

    f32x4 o[16];
    #pragma unroll
    for (int n16 = 0; n16 < 16; ++n16) o[n16] = (f32x4){0.f, 0.f, 0.f, 0.f};
    float m[4] = {-1e30f, -1e30f, -1e30f, -1e30f};
    float l[4] = {0.f, 0.f, 0.f, 0.f};

    #define STAGE(J0) { \
        _Pragma("unroll") for (int i = 0; i < 2; ++i) { \
            int base = w * 128 + i * 64; \
            int idx = base + lane; \
            int row = idx >> 3; \
            int c16 = (idx & 7) ^ (row & 7); \
            gl_lds16(kg + ((size_t)b * LL + (J0) + row) * DQKN + c16 * 8, KsB + base * 16); } \
        _Pragma("unroll") for (int i = 0; i < 8; ++i) { \
            int base = w * 512 + i * 64; \
            int idx = base + lane; \
            int n = idx >> 3; \
            int c16 = (idx & 7) ^ (n & 7); \
            gl_lds16(vTg + ((size_t)b * DVN + n) * LL + (J0) + c16 * 8, VsB + base * 16); } }

    for (int tt = 0; tt < nt; ++tt) {
        const int j0 = jlo + tt * 64;
        __syncthreads();       // done reading previous tile (also covers btl writes)
        STAGE(j0);
        __syncthreads();       // drains vmcnt; tile visible
        // QK^T (q pre-scaled by SCALE*LOG2E)
        f32x4 s[4];
        #pragma unroll
        for (int t16 = 0; t16 < 4; ++t16) s[t16] = (f32x4){0.f, 0.f, 0.f, 0.f};
        #pragma unroll
        for (int c = 0; c < 2; ++c) {
            #pragma unroll
            for (int t16 = 0; t16 < 4; ++t16) {
                int j = t16 * 16 + l16;
                s16x8 kf = *reinterpret_cast<const s16x8*>(KsB + j * 128 + ((c * 64 + l4 * 16) ^ ((j & 7) << 4)));
                s[t16] = __builtin_amdgcn_mfma_f32_16x16x32_bf16(qf[c], kf, s[t16], 0, 0, 0);
            }
        }
        // bias+mask via extended table; row stats
        const int Cb = (i0 + w * 16 + l4 * 4) - (j0 + l16) - dminE;
        float sv[4][4];
        float rmax[4] = {-1e30f, -1e30f, -1e30f, -1e30f};
        #pragma unroll
        for (int t16 = 0; t16 < 4; ++t16) {
            #pragma unroll
            for (int r = 0; r < 4; ++r) {
                float val = s[t16][r] + btl[Cb + r - t16 * 16];
                sv[t16][r] = val;
                rmax[r] = fmaxf(rmax[r], val);
            }
        }
        #pragma unroll
        for (int off = 1; off < 16; off <<= 1) {
            #pragma unroll
            for (int r = 0; r < 4; ++r) rmax[r] = fmaxf(rmax[r], __shfl_xor(rmax[r], off));
        }
        // defer-max: rescale only when the max grows by more than THR=8 (log2 domain)
        bool need = (rmax[0] > m[0] + 8.f) || (rmax[1] > m[1] + 8.f) ||
                    (rmax[2] > m[2] + 8.f) || (rmax[3] > m[3] + 8.f);
        if (__any(need)) {
            float alpha[4];
            #pragma unroll
            for (int r = 0; r < 4; ++r) {
                float mn = fmaxf(m[r], rmax[r]);
                alpha[r] = exp2f(m[r] - mn);
                m[r] = mn;
                l[r] *= alpha[r];
            }
            #pragma unroll
            for (int n16 = 0; n16 < 16; ++n16) {
                #pragma unroll
                for (int r = 0; r < 4; ++r) o[n16][r] *= alpha[r];
            }
        }
        #pragma unroll
        for (int t16 = 0; t16 < 4; ++t16) {
            #pragma unroll
            for (int r = 0; r < 4; ++r) {
                float p = exp2f(sv[t16][r] - m[r]);
                Ps[w][l4 * 4 + r][t16 * 16 + l16] = f2bf(p);
            }
        }
        // PV + row-sum via ones-MFMA (Ps wave-private)
        f32x4 lacc = (f32x4){0.f, 0.f, 0.f, 0.f};
        #pragma unroll
        for (int c = 0; c < 2; ++c) {
            s16x8 pf = *reinterpret_cast<const s16x8*>(&Ps[w][l16][c * 32 + l4 * 8]);
            lacc = __builtin_amdgcn_mfma_f32_16x16x32_bf16(pf, ones, lacc, 0, 0, 0);
            #pragma unroll
            for (int n16 = 0; n16 < 16; ++n16) {
                int n = n16 * 16 + l16;
                s16x8 vf = *reinterpret_cast<const s16x8*>(VsB + n * 128 + ((c * 64 + l4 * 16) ^ ((n & 7) << 4)));
                o[n16] = __builtin_amdgcn_mfma_f32_16x16x32_bf16(pf, vf, o[n16], 0, 0, 0);
            }
        }
        #pragma unroll
        for (int r = 0; r < 4; ++r) l[r] += lacc[r];
    }
    #undef STAGE
    if (ti < 4) {
        float invl[4];
        #pragma unroll
        for (int r = 0; r < 4; ++r) invl[r] = 1.f / l[r];
        #pragma unroll
        for (int n16 = 0; n16 < 16; ++n16) {
            #pragma unroll
            for (int r = 0; r < 4; ++r) {
                aob[((size_t)b * LL + i0 + w * 16 + l4 * 4 + r) * DVN + n16 * 16 + l16] = f2bf(o[n16][r] * invl[r]);
            }
        }
    } else {
        const size_t slot = (size_t)b * NCHK + cid;
        __hip_bfloat16* po = part_o + slot * (64 * 256);
        #pragma unroll
        for (int n16 = 0; n16 < 16; ++n16) {
            #pragma unroll
            for (int r = 0; r < 4; ++r)
                po[(size_t)(w * 16 + l4 * 4 + r) * 256 + n16 * 16 + l16] = f2bf(o[n16][r]);
        }
        if (l16 == 0) {
            #pragma unroll
            for (int r = 0; r < 4; ++r) {
                int row = w * 16 + l4 * 4 + r;
                part_ml[slot * 128 + row * 2]     = m[r];
                part_ml[slot * 128 + row * 2 + 1] = l[r];
            }
        }
    }
}

// ---------------- combine partials (ti >= 4), nc = ti/4+1 in [2,8], col-half split
__global__ __launch_bounds__(256) void attn_combine(const __hip_bfloat16* __restrict__ part_o,
                                                    const float* __restrict__ part_ml,
                                                    __hip_bfloat16* __restrict__ aob) {
    const int ti = 4 + (int)blockIdx.x;   // 4..31
    const int ch = blockIdx.y;            // column half
    const int b = blockIdx.z;
    const int g = ti >> 2;
    const int nc = g + 1;
    const int cid0 = 2*g*(g+1) + (ti - 4*g)*(g+1);
    const size_t slot0 = (size_t)b * NCHK + cid0;
    __shared__ float sW[8][64];
    __shared__ float sinvL[64];
    const int t = threadIdx.x;
    if (t < 64) {
        float M = -1e30f;
        for (int c = 0; c < nc; ++c)
            M = fmaxf(M, part_ml[(slot0 + c) * 128 + t * 2]);
        float L = 0.f;
        for (int c = 0; c < nc; ++c) {
            float wv = exp2f(part_ml[(slot0 + c) * 128 + t * 2] - M);
            sW[c][t] = wv;
            L += wv * part_ml[(slot0 + c) * 128 + t * 2 + 1];
        }
        sinvL[t] = 1.f / L;
    }
    __syncthreads();
    const int i0 = ti * 64;
    #pragma unroll
    for (int it = 0; it < 4; ++it) {
        int idx = it * 256 + t;           // 8-bf16 units over 64 x 128
        int row = idx >> 4, c8 = idx & 15;
        int colu = ch * 16 + c8;          // unit of 8 cols within 256
        float acc[8] = {0.f,0.f,0.f,0.f,0.f,0.f,0.f,0.f};
        for (int c = 0; c < nc; ++c) {
            float wv = sW[c][row];
            uint4 d = *reinterpret_cast<const uint4*>(part_o + (slot0 + c) * (size_t)(64*256) + row * 256 + colu * 8);
            const ushort* pp = (const ushort*)&d;
            #pragma unroll
            for (int j = 0; j < 8; ++j) acc[j] = fmaf(wv, bf2f(pp[j]), acc[j]);
        }
        float il = sinvL[row];
        ushort pk[8];
        #pragma unroll
        for (int j = 0; j < 8; ++j) pk[j] = f2bfu(acc[j] * il);
        *reinterpret_cast<uint4*>(aob + ((size_t)b * LL + i0 + row) * DVN + colu * 8) = *reinterpret_cast<uint4*>(pk);
    }
}

// ---------------- fused final, split by column half (grid.y)
__global__ __launch_bounds__(256) void final_mfma(
        const __hip_bfloat16* __restrict__ emab, const __hip_bfloat16* __restrict__ aob,
        const __hip_bfloat16* __restrict__ rstb, const float* __restrict__ x,
        const __hip_bfloat16* __restrict__ WhP, const __hip_bfloat16* __restrict__ UhP,
        const __hip_bfloat16* __restrict__ WuP, const float* __restrict__ bh,
        const float* __restrict__ bu, float* __restrict__ out) {
    __shared__ char As1[64*256];   // ema tile, K=128
    __shared__ char As2[64*512];   // gated tile, K=256
    const int row0 = blockIdx.x * 64;
    const int ch = blockIdx.y;     // cols [ch*64, ch*64+64)
    const int t = threadIdx.x, w = t>>6, lane = t&63, l16 = lane&15, l4 = lane>>4;
    #pragma unroll
    for (int p = 0; p < 4; ++p) {
        int idx = p*256 + t;
        int row = idx / 16, u = idx % 16;
        uint4 d = *reinterpret_cast<const uint4*>(emab + (size_t)(row0+row)*DD + u*8);
        *reinterpret_cast<uint4*>(As1 + row*256 + ((u*16) ^ ((row&7)<<4))) = d;
    }
    #pragma unroll
    for (int p = 0; p < 8; ++p) {
        int idx = p*256 + t;
        int row = idx / 32, u = idx % 32;
        uint4 da = *reinterpret_cast<const uint4*>(aob + (size_t)(row0+row)*DVN + u*8);
        uint4 dr = *reinterpret_cast<const uint4*>(rstb + (size_t)(row0+row)*DVN + u*8);
        const ushort* pa = (const ushort*)&da;
        const ushort* pr = (const ushort*)&dr;
        ushort gg[8];
        #pragma unroll
        for (int j = 0; j < 8; ++j) gg[j] = f2bfu(bf2f(pa[j]) * bf2f(pr[j]));
        *reinterpret_cast<uint4*>(As2 + row*512 + ((u*16) ^ ((row&7)<<4))) = *reinterpret_cast<uint4*>(gg);
    }
    __syncthreads();
    f32x4 acc1[4], acc2[4];
    #pragma unroll
    for (int n = 0; n < 4; ++n) { acc1[n] = (f32x4){0.f,0.f,0.f,0.f}; acc2[n] = (f32x4){0.f,0.f,0.f,0.f}; }
    const int arow = w*16 + l16;
    #pragma unroll
    for (int k32 = 0; k32 < 4; ++k32) {
        s16x8 af = *reinterpret_cast<const s16x8*>(As1 + arow*256 + ((k32*64 + l4*16) ^ ((arow&7)<<4)));
        #pragma unroll
        for (int n = 0; n < 4; ++n) {
            s16x8 bw = *reinterpret_cast<const s16x8*>(WhP + ((size_t)((ch*4+n)*4 + k32)*64 + lane)*8);
            acc1[n] = __builtin_amdgcn_mfma_f32_16x16x32_bf16(af, bw, acc1[n], 0, 0, 0);
            s16x8 bu2 = *reinterpret_cast<const s16x8*>(WuP + ((size_t)((ch*4+n)*4 + k32)*64 + lane)*8);
            acc2[n] = __builtin_amdgcn_mfma_f32_16x16x32_bf16(af, bu2, acc2[n], 0, 0, 0);
        }
    }
    #pragma unroll
    for (int k32 = 0; k32 < 8; ++k32) {
        s16x8 gf = *reinterpret_cast<const s16x8*>(As2 + arow*512 + ((k32*64 + l4*16) ^ ((arow&7)<<4)));
        #pragma unroll
        for (int n = 0; n < 4; ++n) {
            s16x8 bw = *reinterpret_cast<const s16x8*>(UhP + ((size_t)((ch*4+n)*8 + k32)*64 + lane)*8);
            acc1[n] = __builtin_amdgcn_mfma_f32_16x16x32_bf16(gf, bw, acc1[n], 0, 0, 0);
        }
    }
    #pragma unroll
    for (int n = 0; n < 4; ++n) {
        int col = ch*64 + n*16 + l16;
        float bbh = bh[col], bbu = bu[col];
        #pragma unroll
        for (int r = 0; r < 4; ++r) {
            int row = w*16 + l4*4 + r;
            size_t gidx = (size_t)(row0+row)*DD + col;
            float hh = siluf_(acc1[n][r] + bbh);
            float u = sigmoidf_(acc2[n][r] + bbu);
            float xv = x[gidx];
            out[gidx] = u*hh + (1.f-u)*xv;
        }
    }
}

extern "C" void kernel_launch(void* const* d_in, const int* in_sizes, int n_in,
                              void* d_out, int out_size, void* d_ws, size_t ws_size,
                              hipStream_t stream) {
    const float* x        = (const float*)d_in[0];
    const float* expansion= (const float*)d_in[1];
    const float* reduction= (const float*)d_in[2];
    const float* alphas   = (const float*)d_in[3];
    const float* damps    = (const float*)d_in[4];
    const float* rel_bias = (const float*)d_in[5];
    const float* W_qk     = (const float*)d_in[6];
    const float* b_qk     = (const float*)d_in[7];
    const float* gamma    = (const float*)d_in[8];
    const float* beta     = (const float*)d_in[9];
    const float* W_v      = (const float*)d_in[10];
    const float* b_v      = (const float*)d_in[11];
    const float* W_reset  = (const float*)d_in[12];
    const float* b_reset  = (const float*)d_in[13];
    const float* W_update = (const float*)d_in[14];
    const float* b_update = (const float*)d_in[15];
    const float* Wh       = (const float*)d_in[16];
    const float* Uh       = (const float*)d_in[17];
    const float* bh       = (const float*)d_in[18];
    float* out = (float*)d_out;

    char* base = (char*)d_ws;
    __hip_bfloat16* emab = (__hip_bfloat16*)base;  base += (size_t)MTOT * DD * 2;
    __hip_bfloat16* xb   = (__hip_bfloat16*)base;  base += (size_t)MTOT * DD * 2;
    __hip_bfloat16* qb   = (__hip_bfloat16*)base;  base += (size_t)MTOT * DQKN * 2;
    __hip_bfloat16* kb   = (__hip_bfloat16*)base;  base += (size_t)MTOT * DQKN * 2;
    __hip_bfloat16* vT   = (__hip_bfloat16*)base;  base += (size_t)MTOT * DVN * 2;
    __hip_bfloat16* rstb = (__hip_bfloat16*)base;  base += (size_t)MTOT * DVN * 2;
    __hip_bfloat16* aob  = (__hip_bfloat16*)base;  base += (size_t)MTOT * DVN * 2;
    float* btab  = (float*)base;                   base += (size_t)LL * 4;
    float* sl    = (float*)base;                   base += (size_t)BB * NCH * 16 * DD * 4;
    float* carry = (float*)base;                   base += (size_t)BB * NCH * 16 * DD * 4;
    __hip_bfloat16* WqkP = (__hip_bfloat16*)base;  base += (size_t)DD * DQKN * 2;
    __hip_bfloat16* WvP  = (__hip_bfloat16*)base;  base += (size_t)DD * DVN * 2;
    __hip_bfloat16* WrstP= (__hip_bfloat16*)base;  base += (size_t)DD * DVN * 2;
    __hip_bfloat16* WuP  = (__hip_bfloat16*)base;  base += (size_t)DD * DD * 2;
    __hip_bfloat16* WhP  = (__hip_bfloat16*)base;  base += (size_t)DD * DD * 2;
    __hip_bfloat16* UhP  = (__hip_bfloat16*)base;  base += (size_t)DVN * DD * 2;
    __hip_bfloat16* part_o = (__hip_bfloat16*)base; base += (size_t)BB * NCHK * 64 * 256 * 2;
    float* part_ml = (float*)base;                 base += (size_t)BB * NCHK * 128 * 4;

    pack_all<<<273, 64, 0, stream>>>(W_qk, W_v, W_reset, W_update, Wh, Uh, rel_bias,
                                     WqkP, WvP, WrstP, WuP, WhP, UhP, btab);

    ema_scanA<<<BB * NCH * DD / 256, 256, 0, stream>>>(x, alphas, damps, sl);
    ema_scanB<<<BB * 16 * DD / 256, 256, 0, stream>>>(alphas, damps, sl, carry);
    ema_scanC<<<BB * NCH * DD / 256, 256, 0, stream>>>(x, expansion, reduction, alphas, damps, carry, emab, xb);

    gemm_qk<<<MTOT/64, 256, 0, stream>>>(emab, WqkP, b_qk, gamma, beta, qb, kb);
    gemm_vrst<<<dim3(MTOT/64, 2), 256, 0, stream>>>(xb, emab, WvP, WrstP, b_v, b_reset, vT, rstb);

    attn_kernel<<<dim3(NCHK, BB), 256, 0, stream>>>(qb, kb, vT, btab, aob, part_o, part_ml);
    attn_combine<<<dim3(28, 2, BB), 256, 0, stream>>>(part_o, part_ml, aob);

    final_mfma<<<dim3(MTOT/64, 2), 256, 0, stream>>>(emab, aob, rstb, x, WhP, UhP, WuP, bh, b_update, out);
}

// Round 10
// 117.590 us; speedup vs baseline: 1.1645x; 1.0946x over previous
//
#include <hip/hip_runtime.h>
#include <hip/hip_bf16.h>
#include <math.h>

#define BB 8
#define LL 2048
#define DD 128
#define DQKN 64
#define DVN 256
#define MTOT (BB*LL)
#define SCALE 0.08838834764831845f  // 128^-0.5
#define LOG2E 1.4426950408889634f
#define QSCALE (SCALE*LOG2E)

#define CHUNK 32
#define NCH (LL/CHUNK)   // 64
#define CT 4             // KV tiles (of 64) per attn chunk-block
#define NCHK 144         // chunks per batch = sum_{g=0..7} 4*(g+1)

typedef __attribute__((ext_vector_type(4))) float f32x4;
typedef __attribute__((ext_vector_type(8))) short s16x8;

__device__ __forceinline__ float sigmoidf_(float x){ return 1.f/(1.f+__expf(-x)); }
__device__ __forceinline__ float siluf_(float x){ return x/(1.f+__expf(-x)); }
__device__ __forceinline__ __hip_bfloat16 f2bf(float f){ return __float2bfloat16(f); }
__device__ __forceinline__ ushort f2bfu(float f){ __hip_bfloat16 h = __float2bfloat16(f); return *(const ushort*)&h; }
__device__ __forceinline__ float bf2f(ushort u){ union{unsigned i; float f;} v; v.i = ((unsigned)u)<<16; return v.f; }

__device__ __forceinline__ void gl_lds16(const __hip_bfloat16* g, void* l) {
    __builtin_amdgcn_global_load_lds(
        (const __attribute__((address_space(1))) void*)g,
        (__attribute__((address_space(3))) void*)l, 16, 0, 0);
}

// ---------------- fused: pack all weights + bias table (1 launch)
__global__ void pack_all(const float* __restrict__ Wqk, const float* __restrict__ Wv,
                         const float* __restrict__ Wrst, const float* __restrict__ Wu,
                         const float* __restrict__ Wh, const float* __restrict__ Uh,
                         const float* __restrict__ rel_bias,
                         __hip_bfloat16* __restrict__ WqkP, __hip_bfloat16* __restrict__ WvP,
                         __hip_bfloat16* __restrict__ WrstP, __hip_bfloat16* __restrict__ WuP,
                         __hip_bfloat16* __restrict__ WhP, __hip_bfloat16* __restrict__ UhP,
                         float* __restrict__ btab) {
    int blk = blockIdx.x;
    int l = threadIdx.x;  // 64
    if (blk == 272) {
        for (int n = l; n < LL; n += 64) {
            int bucket;
            if (n < 16) bucket = n;
            else {
                float v = logf((float)n * (1.0f/16.0f)) * (1.0f/logf(8.0f)) * 16.0f;
                bucket = 16 + (int)v;
                if (bucket > 31) bucket = 31;
            }
            btab[n] = rel_bias[bucket] * 8.0f * LOG2E;
        }
        return;
    }
    const float* W; __hip_bfloat16* Wp; int K, N;
    if (blk < 16)       { W=Wqk;  Wp=WqkP;  K=128; N=64; }
    else if (blk < 80)  { W=Wv;   Wp=WvP;   K=128; N=256; blk-=16; }
    else if (blk < 144) { W=Wrst; Wp=WrstP; K=128; N=256; blk-=80; }
    else if (blk < 176) { W=Wu;   Wp=WuP;   K=128; N=128; blk-=144; }
    else if (blk < 208) { W=Wh;   Wp=WhP;   K=128; N=128; blk-=176; }
    else                { W=Uh;   Wp=UhP;   K=256; N=128; blk-=208; }
    int k32 = blk % (K/32), n16 = blk / (K/32);
    int col = n16*16 + (l & 15);
    int krow = k32*32 + (l >> 4)*8;
    ushort tmp[8];
    #pragma unroll
    for (int j = 0; j < 8; ++j) tmp[j] = f2bfu(W[(size_t)(krow + j)*N + col]);
    *reinterpret_cast<uint4*>(Wp + ((size_t)blk*64 + l)*8) = *reinterpret_cast<uint4*>(tmp);
}

// ---------------- EMA chunked scan; A also emits bf16 x
__global__ __launch_bounds__(256) void ema_scanA(const float* __restrict__ x,
                                                 const float* __restrict__ alphas,
                                                 const float* __restrict__ damps,
                                                 float* __restrict__ sl,
                                                 __hip_bfloat16* __restrict__ xb) {
    int tid = blockIdx.x * 256 + threadIdx.x;   // 65536
    int d = tid & 127;
    int c = (tid >> 7) & (NCH - 1);
    int b = tid >> 13;
    float u[16], r[16];
    #pragma unroll
    for (int h = 0; h < 16; ++h) {
        float a = sigmoidf_(alphas[h]);
        r[h] = (1.f - a) * sigmoidf_(damps[h]);
        u[h] = 0.f;
    }
    const float* xp = x + ((size_t)b * LL + c * CHUNK) * DD + d;
    __hip_bfloat16* xbp = xb + ((size_t)b * LL + c * CHUNK) * DD + d;
    #pragma unroll 4
    for (int i = 0; i < CHUNK; ++i) {
        float xv = xp[(size_t)i * DD];
        xbp[(size_t)i * DD] = f2bf(xv);
        #pragma unroll
        for (int h = 0; h < 16; ++h) u[h] = fmaf(r[h], u[h], xv);
    }
    float* slp = sl + ((size_t)b * NCH + c) * 16 * DD + d;
    #pragma unroll
    for (int h = 0; h < 16; ++h) slp[(size_t)h * DD] = u[h];
}

__global__ __launch_bounds__(256) void ema_scanB(const float* __restrict__ alphas,
                                                 const float* __restrict__ damps,
                                                 const float* __restrict__ sl,
                                                 float* __restrict__ carry) {
    int tid = blockIdx.x * 256 + threadIdx.x;   // 16384
    int d = tid & 127;
    int h = (tid >> 7) & 15;
    int b = tid >> 11;
    float a = sigmoidf_(alphas[h]);
    float r = (1.f - a) * sigmoidf_(damps[h]);
    float rC = r;
    #pragma unroll
    for (int q = 0; q < 5; ++q) rC *= rC;       // r^32
    const float* slp = sl + ((size_t)b * NCH * 16 + h) * DD + d;
    float* cp = carry + ((size_t)b * NCH * 16 + h) * DD + d;
    float u = 0.f;
    #pragma unroll 8
    for (int c = 0; c < NCH; ++c) {
        cp[(size_t)c * 16 * DD] = u;
        u = slp[(size_t)c * 16 * DD] + rC * u;
    }
}

// Pass C: scan with carry (reads bf16 x), emit ema (bf16)
__global__ __launch_bounds__(256) void ema_scanC(const __hip_bfloat16* __restrict__ xb,
                                                 const float* __restrict__ expansion,
                                                 const float* __restrict__ reduction,
                                                 const float* __restrict__ alphas,
                                                 const float* __restrict__ damps,
                                                 const float* __restrict__ carry,
                                                 __hip_bfloat16* __restrict__ emab) {
    int tid = blockIdx.x * 256 + threadIdx.x;   // 65536
    int d = tid & 127;
    int c = (tid >> 7) & (NCH - 1);
    int b = tid >> 13;
    float u[16], r[16], we[16];
    #pragma unroll
    for (int h = 0; h < 16; ++h) {
        float a = sigmoidf_(alphas[h]);
        r[h] = (1.f - a) * sigmoidf_(damps[h]);
        we[h] = reduction[h * DD + d] * a * expansion[h * DD + d];
        u[h] = carry[((size_t)b * NCH + c) * 16 * DD + (size_t)h * DD + d];
    }
    const __hip_bfloat16* xp = xb + ((size_t)b * LL + c * CHUNK) * DD + d;
    __hip_bfloat16* ep = emab + ((size_t)b * LL + c * CHUNK) * DD + d;
    #pragma unroll 4
    for (int i = 0; i < CHUNK; ++i) {
        float xv = __bfloat162float(xp[(size_t)i * DD]);
        float acc = 0.f;
        #pragma unroll
        for (int h = 0; h < 16; ++h) {
            u[h] = fmaf(r[h], u[h], xv);
            acc = fmaf(we[h], u[h], acc);
        }
        ep[(size_t)i * DD] = f2bf(acc);
    }
}

// ---------------- fused GEMM: grid.y: 0 = V->vT, 1 = RST, 2 = QK (q,k)
__global__ __launch_bounds__(256) void gemm_fused(const __hip_bfloat16* __restrict__ xb,
        const __hip_bfloat16* __restrict__ emab,
        const __hip_bfloat16* __restrict__ WvP, const __hip_bfloat16* __restrict__ WrstP,
        const __hip_bfloat16* __restrict__ WqkP,
        const float* __restrict__ b_v, const float* __restrict__ b_rst,
        const float* __restrict__ b_qk, const float* __restrict__ gamma,
        const float* __restrict__ beta,
        __hip_bfloat16* __restrict__ vT, __hip_bfloat16* __restrict__ rstb,
        __hip_bfloat16* __restrict__ qb, __hip_bfloat16* __restrict__ kb) {
    __shared__ char AsB[64*256];
    const int mode = blockIdx.y;
    const __hip_bfloat16* A = (mode == 0) ? xb : emab;
    const int row0 = blockIdx.x * 64;
    const int t = threadIdx.x, w = t>>6, lane = t&63, l16 = lane&15, l4 = lane>>4;
    #pragma unroll
    for (int p = 0; p < 4; ++p) {
        int idx = p*256 + t;
        int row = idx / 16, u = idx % 16;
        uint4 d = *reinterpret_cast<const uint4*>(A + (size_t)(row0+row)*DD + u*8);
        *reinterpret_cast<uint4*>(AsB + row*256 + ((u*16) ^ ((row&7)<<4))) = d;
    }
    __syncthreads();
    const int arow = w*16 + l16;
    if (mode == 2) {
        f32x4 acc[4];
        #pragma unroll
        for (int n = 0; n < 4; ++n) acc[n] = (f32x4){0.f,0.f,0.f,0.f};
        #pragma unroll
        for (int k32 = 0; k32 < 4; ++k32) {
            s16x8 af = *reinterpret_cast<const s16x8*>(AsB + arow*256 + ((k32*64 + l4*16) ^ ((arow&7)<<4)));
            #pragma unroll
            for (int n = 0; n < 4; ++n) {
                s16x8 bfr = *reinterpret_cast<const s16x8*>(WqkP + ((size_t)(n*4 + k32)*64 + lane)*8);
                acc[n] = __builtin_amdgcn_mfma_f32_16x16x32_bf16(af, bfr, acc[n], 0, 0, 0);
            }
        }
        #pragma unroll
        for (int n = 0; n < 4; ++n) {
            int col = n*16 + l16;
            float bb = b_qk[col];
            float g0 = gamma[col], g1 = gamma[DQKN + col];
            float be0 = beta[col], be1 = beta[DQKN + col];
            #pragma unroll
            for (int r = 0; r < 4; ++r) {
                int row = w*16 + l4*4 + r;
                float s = siluf_(acc[n][r] + bb);
                qb[(size_t)(row0+row)*DQKN + col] = f2bf((s*g0 + be0) * QSCALE);
                kb[(size_t)(row0+row)*DQKN + col] = f2bf(s*g1 + be1);
            }
        }
        return;
    }
    const __hip_bfloat16* Wp = mode ? WrstP : WvP;
    const float* bias = mode ? b_rst : b_v;
    f32x4 acc[16];
    #pragma unroll
    for (int n = 0; n < 16; ++n) acc[n] = (f32x4){0.f,0.f,0.f,0.f};
    #pragma unroll
    for (int k32 = 0; k32 < 4; ++k32) {
        s16x8 af = *reinterpret_cast<const s16x8*>(AsB + arow*256 + ((k32*64 + l4*16) ^ ((arow&7)<<4)));
        #pragma unroll
        for (int n = 0; n < 16; ++n) {
            s16x8 bfr = *reinterpret_cast<const s16x8*>(Wp + ((size_t)(n*4 + k32)*64 + lane)*8);
            acc[n] = __builtin_amdgcn_mfma_f32_16x16x32_bf16(af, bfr, acc[n], 0, 0, 0);
        }
    }
    if (mode == 0) {
        int bb_i = row0 >> 11;
        int lpos0 = (row0 & 2047) + w*16 + l4*4;
        #pragma unroll
        for (int n = 0; n < 16; ++n) {
            int col = n*16 + l16;
            float bb = bias[col];
            ushort pk[4];
            #pragma unroll
            for (int r = 0; r < 4; ++r) pk[r] = f2bfu(siluf_(acc[n][r] + bb));
            *reinterpret_cast<ushort4*>(vT + ((size_t)bb_i*DVN + col)*LL + lpos0) = *reinterpret_cast<ushort4*>(pk);
        }
    } else {
        #pragma unroll
        for (int n = 0; n < 16; ++n) {
            int col = n*16 + l16;
            float bb = bias[col];
            #pragma unroll
            for (int r = 0; r < 4; ++r) {
                int row = w*16 + l4*4 + r;
                rstb[(size_t)(row0+row)*DVN + col] = f2bf(siluf_(acc[n][r] + bb));
            }
        }
    }
}

// ---------------- MFMA flash attention, split-KV CT=4, global_load_lds staging (R7 config)
// grid (BB, NCHK): bid%8 == batch -> per-XCD L2 holds one batch's K/V
__global__ __launch_bounds__(256) void attn_kernel(
    const __hip_bfloat16* __restrict__ qg, const __hip_bfloat16* __restrict__ kg,
    const __hip_bfloat16* __restrict__ vTg, const float* __restrict__ btab,
    __hip_bfloat16* __restrict__ aob, __hip_bfloat16* __restrict__ part_o,
    float* __restrict__ part_ml) {
    __shared__ __hip_bfloat16 Ks[64 * 64];      // linear fill; swizzle folded into global src
    __shared__ __hip_bfloat16 Vs[256 * 64];
    __shared__ __hip_bfloat16 Ps[4][16][72];
    __shared__ float btl[320];
    const int cid = NCHK - 1 - (int)blockIdx.y; // big groups first
    const int b = blockIdx.x;
    int g = 0;
    while (cid >= 2*(g+1)*(g+2)) ++g;           // group = ti>>2
    const int rel = cid - 2*g*(g+1);
    const int ti = 4*g + rel/(g+1);
    const int cch = rel % (g+1);
    const int i0 = ti * 64;
    const int jlo = cch * (CT*64);
    int jhi = jlo + CT*64; { int je = (ti+1)*64; if (jhi > je) jhi = je; }
    const int nt = (jhi - jlo) >> 6;
    const int t = threadIdx.x;
    const int w = t >> 6, lane = t & 63;
    const int l16 = lane & 15, l4 = lane >> 4;
    char* KsB = (char*)Ks;
    char* VsB = (char*)Vs;

    int dmin = i0 - jhi + 1; if (dmin < 0) dmin = 0;
    const int cnt = (i0 + 63 - jlo) - dmin + 1;
    for (int idx = t; idx < cnt; idx += 256) btl[idx] = btab[dmin + idx];

    const int irow = i0 + w * 16 + l16;
    s16x8 qf[2];
    qf[0] = *reinterpret_cast<const s16x8*>(qg + ((size_t)b * LL + irow) * DQKN + l4 * 8);
    qf[1] = *reinterpret_cast<const s16x8*>(qg + ((size_t)b * LL + irow) * DQKN + 32 + l4 * 8);

    f32x4 o[16];
    #pragma unroll
    for (int n16 = 0; n16 < 16; ++n16) o[n16] = (f32x4){0.f, 0.f, 0.f, 0.f};
    float m[4] = {-1e30f, -1e30f, -1e30f, -1e30f};
    float l[4] = {0.f, 0.f, 0.f, 0.f};

    for (int tt = 0; tt < nt; ++tt) {
        const int j0 = jlo + tt * 64;
        __syncthreads();       // done reading previous tile
        // stage K: 512 16B-units, linear LDS, swizzled global src (c16 = u ^ (row&7))
        #pragma unroll
        for (int i = 0; i < 2; ++i) {
            int base = w * 128 + i * 64;
            int idx = base + lane;
            int row = idx >> 3;
            int c16 = (idx & 7) ^ (row & 7);
            gl_lds16(kg + ((size_t)b * LL + j0 + row) * DQKN + c16 * 8, KsB + base * 16);
        }
        // stage V^T: 2048 units
        #pragma unroll
        for (int i = 0; i < 8; ++i) {
            int base = w * 512 + i * 64;
            int idx = base + lane;
            int n = idx >> 3;
            int c16 = (idx & 7) ^ (n & 7);
            gl_lds16(vTg + ((size_t)b * DVN + n) * LL + j0 + c16 * 8, VsB + base * 16);
        }
        __syncthreads();       // drains vmcnt; tile visible
        // QK^T (q pre-scaled by SCALE*LOG2E)
        f32x4 s[4];
        #pragma unroll
        for (int t16 = 0; t16 < 4; ++t16) s[t16] = (f32x4){0.f, 0.f, 0.f, 0.f};
        #pragma unroll
        for (int c = 0; c < 2; ++c) {
            #pragma unroll
            for (int t16 = 0; t16 < 4; ++t16) {
                int j = t16 * 16 + l16;
                s16x8 kf = *reinterpret_cast<const s16x8*>(KsB + j * 128 + ((c * 64 + l4 * 16) ^ ((j & 7) << 4)));
                s[t16] = __builtin_amdgcn_mfma_f32_16x16x32_bf16(qf[c], kf, s[t16], 0, 0, 0);
            }
        }
        float sv[4][4];
        float rmax[4] = {-1e30f, -1e30f, -1e30f, -1e30f};
        #pragma unroll
        for (int t16 = 0; t16 < 4; ++t16) {
            #pragma unroll
            for (int r = 0; r < 4; ++r) {
                int row = l4 * 4 + r;
                int dlt = (i0 + w * 16 + row) - (j0 + t16 * 16 + l16);
                int bi = dlt - dmin; if (bi < 0) bi = 0;
                float bv = btl[bi];
                float val = (dlt >= 0) ? (s[t16][r] + bv) : -1e30f;
                sv[t16][r] = val;
                rmax[r] = fmaxf(rmax[r], val);
            }
        }
        #pragma unroll
        for (int off = 1; off < 16; off <<= 1) {
            #pragma unroll
            for (int r = 0; r < 4; ++r) rmax[r] = fmaxf(rmax[r], __shfl_xor(rmax[r], off));
        }
        bool need = (rmax[0] > m[0]) || (rmax[1] > m[1]) || (rmax[2] > m[2]) || (rmax[3] > m[3]);
        if (__any(need)) {
            float alpha[4];
            #pragma unroll
            for (int r = 0; r < 4; ++r) {
                float mn = fmaxf(m[r], rmax[r]);
                alpha[r] = exp2f(m[r] - mn);
                m[r] = mn;
                l[r] *= alpha[r];
            }
            #pragma unroll
            for (int n16 = 0; n16 < 16; ++n16) {
                #pragma unroll
                for (int r = 0; r < 4; ++r) o[n16][r] *= alpha[r];
            }
        }
        float psum[4] = {0.f, 0.f, 0.f, 0.f};
        #pragma unroll
        for (int t16 = 0; t16 < 4; ++t16) {
            #pragma unroll
            for (int r = 0; r < 4; ++r) {
                float p = exp2f(sv[t16][r] - m[r]);
                psum[r] += p;
                Ps[w][l4 * 4 + r][t16 * 16 + l16] = f2bf(p);
            }
        }
        #pragma unroll
        for (int off = 1; off < 16; off <<= 1) {
            #pragma unroll
            for (int r = 0; r < 4; ++r) psum[r] += __shfl_xor(psum[r], off);
        }
        #pragma unroll
        for (int r = 0; r < 4; ++r) l[r] += psum[r];
        // PV (Ps wave-private)
        #pragma unroll
        for (int c = 0; c < 2; ++c) {
            s16x8 pf = *reinterpret_cast<const s16x8*>(&Ps[w][l16][c * 32 + l4 * 8]);
            #pragma unroll
            for (int n16 = 0; n16 < 16; ++n16) {
                int n = n16 * 16 + l16;
                s16x8 vf = *reinterpret_cast<const s16x8*>(VsB + n * 128 + ((c * 64 + l4 * 16) ^ ((n & 7) << 4)));
                o[n16] = __builtin_amdgcn_mfma_f32_16x16x32_bf16(pf, vf, o[n16], 0, 0, 0);
            }
        }
    }
    if (ti < 4) {
        float invl[4];
        #pragma unroll
        for (int r = 0; r < 4; ++r) invl[r] = 1.f / l[r];
        #pragma unroll
        for (int n16 = 0; n16 < 16; ++n16) {
            #pragma unroll
            for (int r = 0; r < 4; ++r) {
                aob[((size_t)b * LL + i0 + w * 16 + l4 * 4 + r) * DVN + n16 * 16 + l16] = f2bf(o[n16][r] * invl[r]);
            }
        }
    } else {
        const size_t slot = (size_t)b * NCHK + cid;
        __hip_bfloat16* po = part_o + slot * (64 * 256);
        #pragma unroll
        for (int n16 = 0; n16 < 16; ++n16) {
            #pragma unroll
            for (int r = 0; r < 4; ++r)
                po[(size_t)(w * 16 + l4 * 4 + r) * 256 + n16 * 16 + l16] = f2bf(o[n16][r]);
        }
        if (l16 == 0) {
            #pragma unroll
            for (int r = 0; r < 4; ++r) {
                int row = w * 16 + l4 * 4 + r;
                part_ml[slot * 128 + row * 2]     = m[r];
                part_ml[slot * 128 + row * 2 + 1] = l[r];
            }
        }
    }
}

// ---------------- combine partials (ti >= 4), nc = ti/4+1 in [2,8], col-half split
__global__ __launch_bounds__(256) void attn_combine(const __hip_bfloat16* __restrict__ part_o,
                                                    const float* __restrict__ part_ml,
                                                    __hip_bfloat16* __restrict__ aob) {
    const int ti = 4 + (int)blockIdx.x;   // 4..31
    const int ch = blockIdx.y;            // column half
    const int b = blockIdx.z;
    const int g = ti >> 2;
    const int nc = g + 1;
    const int cid0 = 2*g*(g+1) + (ti - 4*g)*(g+1);
    const size_t slot0 = (size_t)b * NCHK + cid0;
    __shared__ float sW[8][64];
    __shared__ float sinvL[64];
    const int t = threadIdx.x;
    if (t < 64) {
        float M = -1e30f;
        for (int c = 0; c < nc; ++c)
            M = fmaxf(M, part_ml[(slot0 + c) * 128 + t * 2]);
        float L = 0.f;
        for (int c = 0; c < nc; ++c) {
            float wv = exp2f(part_ml[(slot0 + c) * 128 + t * 2] - M);
            sW[c][t] = wv;
            L += wv * part_ml[(slot0 + c) * 128 + t * 2 + 1];
        }
        sinvL[t] = 1.f / L;
    }
    __syncthreads();
    const int i0 = ti * 64;
    #pragma unroll
    for (int it = 0; it < 4; ++it) {
        int idx = it * 256 + t;           // 8-bf16 units over 64 x 128
        int row = idx >> 4, c8 = idx & 15;
        int colu = ch * 16 + c8;          // unit of 8 cols within 256
        float acc[8] = {0.f,0.f,0.f,0.f,0.f,0.f,0.f,0.f};
        for (int c = 0; c < nc; ++c) {
            float wv = sW[c][row];
            uint4 d = *reinterpret_cast<const uint4*>(part_o + (slot0 + c) * (size_t)(64*256) + row * 256 + colu * 8);
            const ushort* pp = (const ushort*)&d;
            #pragma unroll
            for (int j = 0; j < 8; ++j) acc[j] = fmaf(wv, bf2f(pp[j]), acc[j]);
        }
        float il = sinvL[row];
        ushort pk[8];
        #pragma unroll
        for (int j = 0; j < 8; ++j) pk[j] = f2bfu(acc[j] * il);
        *reinterpret_cast<uint4*>(aob + ((size_t)b * LL + i0 + row) * DVN + colu * 8) = *reinterpret_cast<uint4*>(pk);
    }
}

// ---------------- fused final, split by column half (grid.y)
__global__ __launch_bounds__(256) void final_mfma(
        const __hip_bfloat16* __restrict__ emab, const __hip_bfloat16* __restrict__ aob,
        const __hip_bfloat16* __restrict__ rstb, const float* __restrict__ x,
        const __hip_bfloat16* __restrict__ WhP, const __hip_bfloat16* __restrict__ UhP,
        const __hip_bfloat16* __restrict__ WuP, const float* __restrict__ bh,
        const float* __restrict__ bu, float* __restrict__ out) {
    __shared__ char As1[64*256];   // ema tile, K=128
    __shared__ char As2[64*512];   // gated tile, K=256
    const int row0 = blockIdx.x * 64;
    const int ch = blockIdx.y;     // cols [ch*64, ch*64+64)
    const int t = threadIdx.x, w = t>>6, lane = t&63, l16 = lane&15, l4 = lane>>4;
    #pragma unroll
    for (int p = 0; p < 4; ++p) {
        int idx = p*256 + t;
        int row = idx / 16, u = idx % 16;
        uint4 d = *reinterpret_cast<const uint4*>(emab + (size_t)(row0+row)*DD + u*8);
        *reinterpret_cast<uint4*>(As1 + row*256 + ((u*16) ^ ((row&7)<<4))) = d;
    }
    #pragma unroll
    for (int p = 0; p < 8; ++p) {
        int idx = p*256 + t;
        int row = idx / 32, u = idx % 32;
        uint4 da = *reinterpret_cast<const uint4*>(aob + (size_t)(row0+row)*DVN + u*8);
        uint4 dr = *reinterpret_cast<const uint4*>(rstb + (size_t)(row0+row)*DVN + u*8);
        const ushort* pa = (const ushort*)&da;
        const ushort* pr = (const ushort*)&dr;
        ushort gg[8];
        #pragma unroll
        for (int j = 0; j < 8; ++j) gg[j] = f2bfu(bf2f(pa[j]) * bf2f(pr[j]));
        *reinterpret_cast<uint4*>(As2 + row*512 + ((u*16) ^ ((row&7)<<4))) = *reinterpret_cast<uint4*>(gg);
    }
    __syncthreads();
    f32x4 acc1[4], acc2[4];
    #pragma unroll
    for (int n = 0; n < 4; ++n) { acc1[n] = (f32x4){0.f,0.f,0.f,0.f}; acc2[n] = (f32x4){0.f,0.f,0.f,0.f}; }
    const int arow = w*16 + l16;
    #pragma unroll
    for (int k32 = 0; k32 < 4; ++k32) {
        s16x8 af = *reinterpret_cast<const s16x8*>(As1 + arow*256 + ((k32*64 + l4*16) ^ ((arow&7)<<4)));
        #pragma unroll
        for (int n = 0; n < 4; ++n) {
            s16x8 bw = *reinterpret_cast<const s16x8*>(WhP + ((size_t)((ch*4+n)*4 + k32)*64 + lane)*8);
            acc1[n] = __builtin_amdgcn_mfma_f32_16x16x32_bf16(af, bw, acc1[n], 0, 0, 0);
            s16x8 bu2 = *reinterpret_cast<const s16x8*>(WuP + ((size_t)((ch*4+n)*4 + k32)*64 + lane)*8);
            acc2[n] = __builtin_amdgcn_mfma_f32_16x16x32_bf16(af, bu2, acc2[n], 0, 0, 0);
        }
    }
    #pragma unroll
    for (int k32 = 0; k32 < 8; ++k32) {
        s16x8 gf = *reinterpret_cast<const s16x8*>(As2 + arow*512 + ((k32*64 + l4*16) ^ ((arow&7)<<4)));
        #pragma unroll
        for (int n = 0; n < 4; ++n) {
            s16x8 bw = *reinterpret_cast<const s16x8*>(UhP + ((size_t)((ch*4+n)*8 + k32)*64 + lane)*8);
            acc1[n] = __builtin_amdgcn_mfma_f32_16x16x32_bf16(gf, bw, acc1[n], 0, 0, 0);
        }
    }
    #pragma unroll
    for (int n = 0; n < 4; ++n) {
        int col = ch*64 + n*16 + l16;
        float bbh = bh[col], bbu = bu[col];
        #pragma unroll
        for (int r = 0; r < 4; ++r) {
            int row = w*16 + l4*4 + r;
            size_t gidx = (size_t)(row0+row)*DD + col;
            float hh = siluf_(acc1[n][r] + bbh);
            float u = sigmoidf_(acc2[n][r] + bbu);
            float xv = x[gidx];
            out[gidx] = u*hh + (1.f-u)*xv;
        }
    }
}

extern "C" void kernel_launch(void* const* d_in, const int* in_sizes, int n_in,
                              void* d_out, int out_size, void* d_ws, size_t ws_size,
                              hipStream_t stream) {
    const float* x        = (const float*)d_in[0];
    const float* expansion= (const float*)d_in[1];
    const float* reduction= (const float*)d_in[2];
    const float* alphas   = (const float*)d_in[3];
    const float* damps    = (const float*)d_in[4];
    const float* rel_bias = (const float*)d_in[5];
    const float* W_qk     = (const float*)d_in[6];
    const float* b_qk     = (const float*)d_in[7];
    const float* gamma    = (const float*)d_in[8];
    const float* beta     = (const float*)d_in[9];
    const float* W_v      = (const float*)d_in[10];
    const float* b_v      = (const float*)d_in[11];
    const float* W_reset  = (const float*)d_in[12];
    const float* b_reset  = (const float*)d_in[13];
    const float* W_update = (const float*)d_in[14];
    const float* b_update = (const float*)d_in[15];
    const float* Wh       = (const float*)d_in[16];
    const float* Uh       = (const float*)d_in[17];
    const float* bh       = (const float*)d_in[18];
    float* out = (float*)d_out;

    char* base = (char*)d_ws;
    __hip_bfloat16* emab = (__hip_bfloat16*)base;  base += (size_t)MTOT * DD * 2;
    __hip_bfloat16* xb   = (__hip_bfloat16*)base;  base += (size_t)MTOT * DD * 2;
    __hip_bfloat16* qb   = (__hip_bfloat16*)base;  base += (size_t)MTOT * DQKN * 2;
    __hip_bfloat16* kb   = (__hip_bfloat16*)base;  base += (size_t)MTOT * DQKN * 2;
    __hip_bfloat16* vT   = (__hip_bfloat16*)base;  base += (size_t)MTOT * DVN * 2;
    __hip_bfloat16* rstb = (__hip_bfloat16*)base;  base += (size_t)MTOT * DVN * 2;
    __hip_bfloat16* aob  = (__hip_bfloat16*)base;  base += (size_t)MTOT * DVN * 2;
    float* btab  = (float*)base;                   base += (size_t)LL * 4;
    float* sl    = (float*)base;                   base += (size_t)BB * NCH * 16 * DD * 4;
    float* carry = (float*)base;                   base += (size_t)BB * NCH * 16 * DD * 4;
    __hip_bfloat16* WqkP = (__hip_bfloat16*)base;  base += (size_t)DD * DQKN * 2;
    __hip_bfloat16* WvP  = (__hip_bfloat16*)base;  base += (size_t)DD * DVN * 2;
    __hip_bfloat16* WrstP= (__hip_bfloat16*)base;  base += (size_t)DD * DVN * 2;
    __hip_bfloat16* WuP  = (__hip_bfloat16*)base;  base += (size_t)DD * DD * 2;
    __hip_bfloat16* WhP  = (__hip_bfloat16*)base;  base += (size_t)DD * DD * 2;
    __hip_bfloat16* UhP  = (__hip_bfloat16*)base;  base += (size_t)DVN * DD * 2;
    __hip_bfloat16* part_o = (__hip_bfloat16*)base; base += (size_t)BB * NCHK * 64 * 256 * 2;
    float* part_ml = (float*)base;                 base += (size_t)BB * NCHK * 128 * 4;

    pack_all<<<273, 64, 0, stream>>>(W_qk, W_v, W_reset, W_update, Wh, Uh, rel_bias,
                                     WqkP, WvP, WrstP, WuP, WhP, UhP, btab);

    ema_scanA<<<BB * NCH * DD / 256, 256, 0, stream>>>(x, alphas, damps, sl, xb);
    ema_scanB<<<BB * 16 * DD / 256, 256, 0, stream>>>(alphas, damps, sl, carry);
    ema_scanC<<<BB * NCH * DD / 256, 256, 0, stream>>>(xb, expansion, reduction, alphas, damps, carry, emab);

    gemm_fused<<<dim3(MTOT/64, 3), 256, 0, stream>>>(xb, emab, WvP, WrstP, WqkP,
                                                     b_v, b_reset, b_qk, gamma, beta,
                                                     vT, rstb, qb, kb);

    attn_kernel<<<dim3(BB, NCHK), 256, 0, stream>>>(qb, kb, vT, btab, aob, part_o, part_ml);
    attn_combine<<<dim3(28, 2, BB), 256, 0, stream>>>(part_o, part_ml, aob);

    final_mfma<<<dim3(MTOT/64, 2), 256, 0, stream>>>(emab, aob, rstb, x, WhP, UhP, WuP, bh, b_update, out);
}